// Round 7
// baseline (1249.665 us; speedup 1.0000x reference)
//
#include <hip/hip_runtime.h>

#define NN 8192
#define NE 262144

typedef short bf16x8 __attribute__((ext_vector_type(8)));
typedef float f32x16 __attribute__((ext_vector_type(16)));
typedef float f32x4 __attribute__((ext_vector_type(4)));

__device__ __forceinline__ unsigned short f2bf(float f) {
  unsigned u = __float_as_uint(f);
  u += 0x7fffu + ((u >> 16) & 1u);
  return (unsigned short)(u >> 16);
}
__device__ __forceinline__ float bflo(unsigned u) { return __uint_as_float(u << 16); }
__device__ __forceinline__ float bfhi(unsigned u) { return __uint_as_float(u & 0xffff0000u); }

// ---- prep: x->bf16, transpose+convert weights, zero counts ----
__global__ void k_prep(const float* __restrict__ x, const float* __restrict__ W1,
                       const float* __restrict__ W2, unsigned short* __restrict__ xb,
                       unsigned short* __restrict__ W1t, unsigned short* __restrict__ W2t,
                       int* __restrict__ counts) {
  int id = blockIdx.x * blockDim.x + threadIdx.x;
  int stride = gridDim.x * blockDim.x;
  // x: 8192*512 floats -> bf16, process float4 chunks
  for (int t = id; t < (NN * 512) / 4; t += stride) {
    float4 v = *(const float4*)(x + (size_t)t * 4);
    unsigned lo = (unsigned)f2bf(v.x) | ((unsigned)f2bf(v.y) << 16);
    unsigned hi = (unsigned)f2bf(v.z) | ((unsigned)f2bf(v.w) << 16);
    *(uint2*)(xb + (size_t)t * 4) = make_uint2(lo, hi);
  }
  for (int t = id; t < 512 * 256; t += stride) {
    int k = t >> 8, c = t & 255;               // W1[k][c] -> W1t[c][k]
    W1t[c * 512 + k] = f2bf(W1[t]);
  }
  for (int t = id; t < 256 * 128; t += stride) {
    int k = t >> 7, c = t & 127;               // W2[k][c] -> W2t[c][k]
    W2t[c * 256 + k] = f2bf(W2[t]);
  }
  for (int t = id; t < NN; t += stride) counts[t] = 0;
}

// ---- CSR build ----
__global__ void k_hist(const int* __restrict__ rows, int* __restrict__ counts) {
  int id = blockIdx.x * blockDim.x + threadIdx.x;
  if (id < NE) atomicAdd(&counts[rows[id]], 1);
}

__global__ void k_scan(const int* __restrict__ counts, int* __restrict__ starts,
                       int* __restrict__ cursor) {
  __shared__ int sums[1024];
  int t = threadIdx.x;
  int base = t * 8;
  int local[8];
  int s = 0;
  #pragma unroll
  for (int i = 0; i < 8; ++i) { local[i] = s; s += counts[base + i]; }
  sums[t] = s;
  __syncthreads();
  for (int off = 1; off < 1024; off <<= 1) {
    int v = 0;
    if (t >= off) v = sums[t - off];
    __syncthreads();
    sums[t] += v;
    __syncthreads();
  }
  int pre = sums[t] - s;
  #pragma unroll
  for (int i = 0; i < 8; ++i) {
    starts[base + i] = pre + local[i];
    cursor[base + i] = pre + local[i];
  }
  if (t == 1023) starts[NN] = sums[1023];
}

// scatter vals/cols directly into CSR order (no perm indirection later)
__global__ void k_scatter(const int* __restrict__ rows, const float* __restrict__ vals,
                          const int* __restrict__ cols, int* __restrict__ cursor,
                          float* __restrict__ ev_s, int* __restrict__ ec_s) {
  int id = blockIdx.x * blockDim.x + threadIdx.x;
  if (id < NE) {
    int pos = atomicAdd(&cursor[rows[id]], 1);
    ev_s[pos] = vals[id];
    ec_s[pos] = cols[id];
  }
}

// ---- GEMM: C[8192][N](bf16) = A[8192][K](bf16) * Bt[N][K]^T (bf16 MFMA) ----
// Tile 128x64, BK=64. 4 waves 2x2, wave tile 64x32. Swapped operands: lane owns row.
template <int K, int N>
__global__ __launch_bounds__(256) void k_gemm(const unsigned short* __restrict__ Ab,
                                              const unsigned short* __restrict__ Bt,
                                              unsigned short* __restrict__ Cb) {
  __shared__ unsigned char As[128 * 64 * 2];   // [128][64] bf16, row=128B, swz ((r&7)<<4)
  __shared__ unsigned char Bs[64 * 64 * 2];
  const int tid = threadIdx.x;
  const int r0 = blockIdx.x * 128, c0 = blockIdx.y * 64;
  const int wid = tid >> 6, lane = tid & 63;
  const int wrow = wid >> 1, wcol = wid & 1;
  const int lr = lane & 31, lg = lane >> 5;

  f32x16 acc[2] = {};

  for (int kc = 0; kc < K; kc += 64) {
    __syncthreads();
    for (int q = tid; q < 1024; q += 256) {
      int r = q >> 3, s = q & 7;
      float4 v = *(const float4*)(Ab + (size_t)(r0 + r) * K + kc + s * 8);
      *(float4*)(As + r * 128 + ((s * 16) ^ ((r & 7) << 4))) = v;
    }
    for (int q = tid; q < 512; q += 256) {
      int r = q >> 3, s = q & 7;
      float4 v = *(const float4*)(Bt + (size_t)(c0 + r) * K + kc + s * 8);
      *(float4*)(Bs + r * 128 + ((s * 16) ^ ((r & 7) << 4))) = v;
    }
    __syncthreads();
    #pragma unroll
    for (int ks = 0; ks < 4; ++ks) {
      int brow = wcol * 32 + lr;
      bf16x8 bf = *(const bf16x8*)(Bs + brow * 128 + ((ks * 32 + lg * 16) ^ ((brow & 7) << 4)));
      #pragma unroll
      for (int m = 0; m < 2; ++m) {
        int arow = wrow * 64 + m * 32 + lr;
        bf16x8 af = *(const bf16x8*)(As + arow * 128 + ((ks * 32 + lg * 16) ^ ((arow & 7) << 4)));
        acc[m] = __builtin_amdgcn_mfma_f32_32x32x16_bf16(bf, af, acc[m], 0, 0, 0);
      }
    }
  }
  // lane owns row = lr (+wave/m offsets); regs span cols: col(r)= (r&3)+8*(r>>2)+4*lg
  #pragma unroll
  for (int m = 0; m < 2; ++m) {
    int row = r0 + wrow * 64 + m * 32 + lr;
    #pragma unroll
    for (int g = 0; g < 4; ++g) {
      unsigned lo = (unsigned)f2bf(acc[m][4 * g + 0]) | ((unsigned)f2bf(acc[m][4 * g + 1]) << 16);
      unsigned hi = (unsigned)f2bf(acc[m][4 * g + 2]) | ((unsigned)f2bf(acc[m][4 * g + 3]) << 16);
      int colc = c0 + wcol * 32 + 8 * g + 4 * lg;
      *(uint2*)(Cb + (size_t)row * N + colc) = make_uint2(lo, hi);
    }
  }
}

// ---- SPMM: one wave per row, CSR, bf16 gather ----
template <int F>
__global__ __launch_bounds__(256) void k_spmm(const int* __restrict__ starts,
                                              const float* __restrict__ ev_s,
                                              const int* __restrict__ ec_s,
                                              const unsigned short* __restrict__ Sb,
                                              float* __restrict__ outF,
                                              unsigned short* __restrict__ outB) {
  constexpr int V = F / 64;   // cols per lane (4 or 2)
  int gw = (blockIdx.x * blockDim.x + threadIdx.x) >> 6;
  int lane = threadIdx.x & 63;
  if (gw >= NN) return;
  int s = starts[gw], e = starts[gw + 1];
  float acc[V];
  #pragma unroll
  for (int v = 0; v < V; ++v) acc[v] = 0.f;
  for (int j = s; j < e; ++j) {
    float w = ev_s[j];
    int c = ec_s[j];
    if constexpr (V == 4) {
      uint2 t = *(const uint2*)(Sb + (size_t)c * F + lane * 4);
      acc[0] += w * bflo(t.x); acc[1] += w * bfhi(t.x);
      acc[2] += w * bflo(t.y); acc[3] += w * bfhi(t.y);
    } else {
      unsigned t = *(const unsigned*)(Sb + (size_t)c * F + lane * 2);
      acc[0] += w * bflo(t); acc[1] += w * bfhi(t);
    }
  }
  #pragma unroll
  for (int v = 0; v < V; ++v) acc[v] = fmaxf(acc[v], 0.f);
  if constexpr (V == 4) {
    unsigned lo = (unsigned)f2bf(acc[0]) | ((unsigned)f2bf(acc[1]) << 16);
    unsigned hi = (unsigned)f2bf(acc[2]) | ((unsigned)f2bf(acc[3]) << 16);
    *(uint2*)(outB + (size_t)gw * F + lane * 4) = make_uint2(lo, hi);
  } else {
    unsigned lo = (unsigned)f2bf(acc[0]) | ((unsigned)f2bf(acc[1]) << 16);
    *(unsigned int*)(outB + (size_t)gw * F + lane * 2) = lo;
    if (outF) {
      *(float2*)(outF + (size_t)gw * F + lane * 2) = make_float2(acc[0], acc[1]);
    }
  }
}

// ---- rec = z z^T to two views (write-BW bound). Swapped operands: lane owns row i.
__global__ __launch_bounds__(256) void k_rec(const unsigned short* __restrict__ zb,
                                             float* __restrict__ out0,
                                             float* __restrict__ out1) {
  __shared__ unsigned char As[128 * 128 * 2];  // i-tile [128][128] bf16, swz ((r&15)<<4)
  __shared__ unsigned char Bs[64 * 128 * 2];   // j-tile [64][128]
  const int tid = threadIdx.x;
  const int i0 = blockIdx.x * 128, j0 = blockIdx.y * 64;

  for (int q = tid; q < 2048; q += 256) {
    int r = q >> 4, s = q & 15;
    float4 v = *(const float4*)(zb + (size_t)(i0 + r) * 128 + s * 8);
    *(float4*)(As + r * 256 + ((s * 16) ^ ((r & 15) << 4))) = v;
  }
  for (int q = tid; q < 1024; q += 256) {
    int r = q >> 4, s = q & 15;
    float4 v = *(const float4*)(zb + (size_t)(j0 + r) * 128 + s * 8);
    *(float4*)(Bs + r * 256 + ((s * 16) ^ ((r & 15) << 4))) = v;
  }
  __syncthreads();

  const int wid = tid >> 6, lane = tid & 63;
  const int wrow = wid >> 1, wcol = wid & 1;
  const int lr = lane & 31, lg = lane >> 5;

  f32x16 acc[2] = {};
  #pragma unroll
  for (int ks = 0; ks < 8; ++ks) {
    int brow = wcol * 32 + lr;
    bf16x8 bf = *(const bf16x8*)(Bs + brow * 256 + ((ks * 32 + lg * 16) ^ ((brow & 15) << 4)));
    #pragma unroll
    for (int m = 0; m < 2; ++m) {
      int arow = wrow * 64 + m * 32 + lr;
      bf16x8 af = *(const bf16x8*)(As + arow * 256 + ((ks * 32 + lg * 16) ^ ((arow & 15) << 4)));
      acc[m] = __builtin_amdgcn_mfma_f32_32x32x16_bf16(bf, af, acc[m], 0, 0, 0);
    }
  }
  #pragma unroll
  for (int m = 0; m < 2; ++m) {
    size_t row = (size_t)(i0 + wrow * 64 + m * 32 + lr);
    #pragma unroll
    for (int g = 0; g < 4; ++g) {
      f32x4 v = {acc[m][4 * g + 0], acc[m][4 * g + 1], acc[m][4 * g + 2], acc[m][4 * g + 3]};
      size_t idx = row * NN + (size_t)(j0 + wcol * 32 + 8 * g + 4 * lg);
      __builtin_nontemporal_store(v, (f32x4*)(out0 + idx));
      __builtin_nontemporal_store(v, (f32x4*)(out1 + idx));
    }
  }
}

extern "C" void kernel_launch(void* const* d_in, const int* in_sizes, int n_in,
                              void* d_out, int out_size, void* d_ws, size_t ws_size,
                              hipStream_t stream) {
  const float* x     = (const float*)d_in[0];
  const float* W1    = (const float*)d_in[1];
  const float* W2    = (const float*)d_in[2];
  const float* evals = (const float*)d_in[3];
  const int*   erows = (const int*)d_in[4];
  const int*   ecols = (const int*)d_in[5];

  float* out_z   = (float*)d_out;                       // [8192][128]
  float* out_r0  = out_z + (size_t)NN * 128;            // view 0
  float* out_r1  = out_r0 + (size_t)NN * NN;            // view 1

  char* w = (char*)d_ws;
  unsigned short* W1t = (unsigned short*)w;  w += 256 * 512 * 2;
  unsigned short* W2t = (unsigned short*)w;  w += 128 * 256 * 2;
  unsigned short* xb  = (unsigned short*)w;  w += (size_t)NN * 512 * 2;
  unsigned short* g1  = (unsigned short*)w;  w += (size_t)NN * 256 * 2;   // x@W1, bf16
  unsigned short* h1  = (unsigned short*)w;  w += (size_t)NN * 256 * 2;   // relu(spmm), bf16
  unsigned short* g2  = (unsigned short*)w;  w += (size_t)NN * 128 * 2;   // h@W2, bf16
  unsigned short* zb  = (unsigned short*)w;  w += (size_t)NN * 128 * 2;   // z, bf16
  int*   counts = (int*)w;                   w += NN * 4;
  int*   starts = (int*)w;                   w += (NN + 8) * 4;
  int*   cursor = (int*)w;                   w += NN * 4;
  float* ev_s   = (float*)w;                 w += NE * 4;
  int*   ec_s   = (int*)w;                   w += NE * 4;

  k_prep<<<256, 256, 0, stream>>>(x, W1, W2, xb, W1t, W2t, counts);
  k_hist<<<NE / 256, 256, 0, stream>>>(erows, counts);
  k_scan<<<1, 1024, 0, stream>>>(counts, starts, cursor);
  k_scatter<<<NE / 256, 256, 0, stream>>>(erows, evals, ecols, cursor, ev_s, ec_s);

  k_gemm<512, 256><<<dim3(64, 4), 256, 0, stream>>>(xb, W1t, g1);
  k_spmm<256><<<NN / 4, 256, 0, stream>>>(starts, ev_s, ec_s, g1, nullptr, h1);
  k_gemm<256, 128><<<dim3(64, 2), 256, 0, stream>>>(h1, W2t, g2);
  k_spmm<128><<<NN / 4, 256, 0, stream>>>(starts, ev_s, ec_s, g2, out_z, zb);
  k_rec<<<dim3(64, 128), 256, 0, stream>>>(zb, out_r0, out_r1);
}

// Round 9
// 701.218 us; speedup vs baseline: 1.7821x; 1.7821x over previous
//
#include <hip/hip_runtime.h>

#define NN 8192
#define NE 262144

typedef short bf16x8 __attribute__((ext_vector_type(8)));
typedef float f32x16 __attribute__((ext_vector_type(16)));
typedef float f32x4 __attribute__((ext_vector_type(4)));

__device__ __forceinline__ unsigned short f2bf(float f) {
  unsigned u = __float_as_uint(f);
  u += 0x7fffu + ((u >> 16) & 1u);
  return (unsigned short)(u >> 16);
}
__device__ __forceinline__ float bflo(unsigned u) { return __uint_as_float(u << 16); }
__device__ __forceinline__ float bfhi(unsigned u) { return __uint_as_float(u & 0xffff0000u); }

// ---- prep: x->bf16, transpose+convert weights, zero counts ----
__global__ void k_prep(const float* __restrict__ x, const float* __restrict__ W1,
                       const float* __restrict__ W2, unsigned short* __restrict__ xb,
                       unsigned short* __restrict__ W1t, unsigned short* __restrict__ W2t,
                       int* __restrict__ counts) {
  int id = blockIdx.x * blockDim.x + threadIdx.x;
  int stride = gridDim.x * blockDim.x;
  for (int t = id; t < (NN * 512) / 4; t += stride) {
    float4 v = *(const float4*)(x + (size_t)t * 4);
    unsigned lo = (unsigned)f2bf(v.x) | ((unsigned)f2bf(v.y) << 16);
    unsigned hi = (unsigned)f2bf(v.z) | ((unsigned)f2bf(v.w) << 16);
    *(uint2*)(xb + (size_t)t * 4) = make_uint2(lo, hi);
  }
  for (int t = id; t < 512 * 256; t += stride) {
    int k = t >> 8, c = t & 255;               // W1[k][c] -> W1t[c][k]
    W1t[c * 512 + k] = f2bf(W1[t]);
  }
  for (int t = id; t < 256 * 128; t += stride) {
    int k = t >> 7, c = t & 127;               // W2[k][c] -> W2t[c][k]
    W2t[c * 256 + k] = f2bf(W2[t]);
  }
  for (int t = id; t < NN; t += stride) counts[t] = 0;
}

// ---- CSR build ----
__global__ void k_hist(const int* __restrict__ rows, int* __restrict__ counts) {
  int id = blockIdx.x * blockDim.x + threadIdx.x;
  if (id < NE) atomicAdd(&counts[rows[id]], 1);
}

__global__ void k_scan(const int* __restrict__ counts, int* __restrict__ starts,
                       int* __restrict__ cursor) {
  __shared__ int sums[1024];
  int t = threadIdx.x;
  int base = t * 8;
  int local[8];
  int s = 0;
  #pragma unroll
  for (int i = 0; i < 8; ++i) { local[i] = s; s += counts[base + i]; }
  sums[t] = s;
  __syncthreads();
  for (int off = 1; off < 1024; off <<= 1) {
    int v = 0;
    if (t >= off) v = sums[t - off];
    __syncthreads();
    sums[t] += v;
    __syncthreads();
  }
  int pre = sums[t] - s;
  #pragma unroll
  for (int i = 0; i < 8; ++i) {
    starts[base + i] = pre + local[i];
    cursor[base + i] = pre + local[i];
  }
  if (t == 1023) starts[NN] = sums[1023];
}

__global__ void k_scatter(const int* __restrict__ rows, const float* __restrict__ vals,
                          const int* __restrict__ cols, int* __restrict__ cursor,
                          float* __restrict__ ev_s, int* __restrict__ ec_s) {
  int id = blockIdx.x * blockDim.x + threadIdx.x;
  if (id < NE) {
    int pos = atomicAdd(&cursor[rows[id]], 1);
    ev_s[pos] = vals[id];
    ec_s[pos] = cols[id];
  }
}

// ---- GEMM: C[8192][N](bf16) = A[8192][K](bf16) * Bt[N][K]^T (bf16 MFMA) ----
template <int K, int N>
__global__ __launch_bounds__(256) void k_gemm(const unsigned short* __restrict__ Ab,
                                              const unsigned short* __restrict__ Bt,
                                              unsigned short* __restrict__ Cb) {
  __shared__ unsigned char As[128 * 64 * 2];
  __shared__ unsigned char Bs[64 * 64 * 2];
  const int tid = threadIdx.x;
  const int r0 = blockIdx.x * 128, c0 = blockIdx.y * 64;
  const int wid = tid >> 6, lane = tid & 63;
  const int wrow = wid >> 1, wcol = wid & 1;
  const int lr = lane & 31, lg = lane >> 5;

  f32x16 acc[2] = {};

  for (int kc = 0; kc < K; kc += 64) {
    __syncthreads();
    for (int q = tid; q < 1024; q += 256) {
      int r = q >> 3, s = q & 7;
      float4 v = *(const float4*)(Ab + (size_t)(r0 + r) * K + kc + s * 8);
      *(float4*)(As + r * 128 + ((s * 16) ^ ((r & 7) << 4))) = v;
    }
    for (int q = tid; q < 512; q += 256) {
      int r = q >> 3, s = q & 7;
      float4 v = *(const float4*)(Bt + (size_t)(c0 + r) * K + kc + s * 8);
      *(float4*)(Bs + r * 128 + ((s * 16) ^ ((r & 7) << 4))) = v;
    }
    __syncthreads();
    #pragma unroll
    for (int ks = 0; ks < 4; ++ks) {
      int brow = wcol * 32 + lr;
      bf16x8 bf = *(const bf16x8*)(Bs + brow * 128 + ((ks * 32 + lg * 16) ^ ((brow & 7) << 4)));
      #pragma unroll
      for (int m = 0; m < 2; ++m) {
        int arow = wrow * 64 + m * 32 + lr;
        bf16x8 af = *(const bf16x8*)(As + arow * 128 + ((ks * 32 + lg * 16) ^ ((arow & 7) << 4)));
        acc[m] = __builtin_amdgcn_mfma_f32_32x32x16_bf16(bf, af, acc[m], 0, 0, 0);
      }
    }
  }
  #pragma unroll
  for (int m = 0; m < 2; ++m) {
    int row = r0 + wrow * 64 + m * 32 + lr;
    #pragma unroll
    for (int g = 0; g < 4; ++g) {
      unsigned lo = (unsigned)f2bf(acc[m][4 * g + 0]) | ((unsigned)f2bf(acc[m][4 * g + 1]) << 16);
      unsigned hi = (unsigned)f2bf(acc[m][4 * g + 2]) | ((unsigned)f2bf(acc[m][4 * g + 3]) << 16);
      int colc = c0 + wcol * 32 + 8 * g + 4 * lg;
      *(uint2*)(Cb + (size_t)row * N + colc) = make_uint2(lo, hi);
    }
  }
}

// ---- SPMM: one wave per row, CSR, bf16 gather ----
template <int F>
__global__ __launch_bounds__(256) void k_spmm(const int* __restrict__ starts,
                                              const float* __restrict__ ev_s,
                                              const int* __restrict__ ec_s,
                                              const unsigned short* __restrict__ Sb,
                                              float* __restrict__ outF,
                                              unsigned short* __restrict__ outB) {
  constexpr int V = F / 64;
  int gw = (blockIdx.x * blockDim.x + threadIdx.x) >> 6;
  int lane = threadIdx.x & 63;
  if (gw >= NN) return;
  int s = starts[gw], e = starts[gw + 1];
  float acc[V];
  #pragma unroll
  for (int v = 0; v < V; ++v) acc[v] = 0.f;
  for (int j = s; j < e; ++j) {
    float w = ev_s[j];
    int c = ec_s[j];
    if constexpr (V == 4) {
      uint2 t = *(const uint2*)(Sb + (size_t)c * F + lane * 4);
      acc[0] += w * bflo(t.x); acc[1] += w * bfhi(t.x);
      acc[2] += w * bflo(t.y); acc[3] += w * bfhi(t.y);
    } else {
      unsigned t = *(const unsigned*)(Sb + (size_t)c * F + lane * 2);
      acc[0] += w * bflo(t); acc[1] += w * bfhi(t);
    }
  }
  #pragma unroll
  for (int v = 0; v < V; ++v) acc[v] = fmaxf(acc[v], 0.f);
  if constexpr (V == 4) {
    unsigned lo = (unsigned)f2bf(acc[0]) | ((unsigned)f2bf(acc[1]) << 16);
    unsigned hi = (unsigned)f2bf(acc[2]) | ((unsigned)f2bf(acc[3]) << 16);
    *(uint2*)(outB + (size_t)gw * F + lane * 4) = make_uint2(lo, hi);
  } else {
    unsigned lo = (unsigned)f2bf(acc[0]) | ((unsigned)f2bf(acc[1]) << 16);
    *(unsigned int*)(outB + (size_t)gw * F + lane * 2) = lo;
    if (outF) {
      *(float2*)(outF + (size_t)gw * F + lane * 2) = make_float2(acc[0], acc[1]);
    }
  }
}

// ---- rec = z z^T to two views. Tile 64(i) x 128(j). LDS-transpose epilogue ->
// each wave stores 2 rows x 512B contiguous (full sectors, fill-like pattern).
__global__ __launch_bounds__(256) void k_rec(const unsigned short* __restrict__ zb,
                                             float* __restrict__ out0,
                                             float* __restrict__ out1) {
  __shared__ unsigned char lds[49152];
  unsigned char* Ai = lds;                 // [64][128] bf16, row=256B, swz ((r&15)<<4)
  unsigned char* Bj = lds + 16384;         // [128][128] bf16
  const int tid = threadIdx.x;
  const int i0 = blockIdx.x * 64, j0 = blockIdx.y * 128;

  for (int q = tid; q < 1024; q += 256) {  // A: 64 rows x 16 slots of 16B
    int r = q >> 4, s = q & 15;
    float4 v = *(const float4*)(zb + (size_t)(i0 + r) * 128 + s * 8);
    *(float4*)(Ai + r * 256 + ((s * 16) ^ ((r & 15) << 4))) = v;
  }
  for (int q = tid; q < 2048; q += 256) {  // B: 128 rows x 16 slots
    int r = q >> 4, s = q & 15;
    float4 v = *(const float4*)(zb + (size_t)(j0 + r) * 128 + s * 8);
    *(float4*)(Bj + r * 256 + ((s * 16) ^ ((r & 15) << 4))) = v;
  }
  __syncthreads();

  const int wid = tid >> 6, lane = tid & 63;
  const int wrow = wid >> 1, wcol = wid & 1;   // wave tile: 32(i) x 64(j)
  const int lr = lane & 31, lg = lane >> 5;

  f32x16 acc[2] = {};
  #pragma unroll
  for (int ks = 0; ks < 8; ++ks) {
    int arow = wrow * 32 + lr;
    bf16x8 af = *(const bf16x8*)(Ai + arow * 256 + ((ks * 32 + lg * 16) ^ ((arow & 15) << 4)));
    #pragma unroll
    for (int m = 0; m < 2; ++m) {
      int brow = wcol * 64 + m * 32 + lr;
      bf16x8 bf = *(const bf16x8*)(Bj + brow * 256 + ((ks * 32 + lg * 16) ^ ((brow & 15) << 4)));
      acc[m] = __builtin_amdgcn_mfma_f32_32x32x16_bf16(bf, af, acc[m], 0, 0, 0);
    }
  }

  // transpose via LDS: T[64][132] f32 (pad 4 -> 16B-aligned rows, modest conflicts)
  __syncthreads();                          // all frag reads done; reuse LDS
  float* T = (float*)lds;
  {
    int row = wrow * 32 + lr;               // i within tile
    #pragma unroll
    for (int m = 0; m < 2; ++m) {
      #pragma unroll
      for (int q = 0; q < 4; ++q) {         // acc[m][4q..4q+3] are 4 consecutive cols
        int col = wcol * 64 + m * 32 + 8 * q + 4 * lg;
        f32x4 v = {acc[m][4 * q + 0], acc[m][4 * q + 1], acc[m][4 * q + 2], acc[m][4 * q + 3]};
        *(f32x4*)(T + row * 132 + col) = v;
      }
    }
  }
  __syncthreads();
  // write out: 8 passes, 8 rows/pass, 32 threads/row -> 512B contiguous per row
  {
    int rr = tid >> 5, cc = (tid & 31) * 4;
    #pragma unroll
    for (int p = 0; p < 8; ++p) {
      int row = p * 8 + rr;
      f32x4 v = *(const f32x4*)(T + row * 132 + cc);
      size_t idx = (size_t)(i0 + row) * NN + (size_t)(j0 + cc);
      __builtin_nontemporal_store(v, (f32x4*)(out0 + idx));
      __builtin_nontemporal_store(v, (f32x4*)(out1 + idx));
    }
  }
}

extern "C" void kernel_launch(void* const* d_in, const int* in_sizes, int n_in,
                              void* d_out, int out_size, void* d_ws, size_t ws_size,
                              hipStream_t stream) {
  const float* x     = (const float*)d_in[0];
  const float* W1    = (const float*)d_in[1];
  const float* W2    = (const float*)d_in[2];
  const float* evals = (const float*)d_in[3];
  const int*   erows = (const int*)d_in[4];
  const int*   ecols = (const int*)d_in[5];

  float* out_z   = (float*)d_out;                       // [8192][128]
  float* out_r0  = out_z + (size_t)NN * 128;            // view 0
  float* out_r1  = out_r0 + (size_t)NN * NN;            // view 1

  char* w = (char*)d_ws;
  unsigned short* W1t = (unsigned short*)w;  w += 256 * 512 * 2;
  unsigned short* W2t = (unsigned short*)w;  w += 128 * 256 * 2;
  unsigned short* xb  = (unsigned short*)w;  w += (size_t)NN * 512 * 2;
  unsigned short* g1  = (unsigned short*)w;  w += (size_t)NN * 256 * 2;   // x@W1, bf16
  unsigned short* h1  = (unsigned short*)w;  w += (size_t)NN * 256 * 2;   // relu(spmm), bf16
  unsigned short* g2  = (unsigned short*)w;  w += (size_t)NN * 128 * 2;   // h@W2, bf16
  unsigned short* zb  = (unsigned short*)w;  w += (size_t)NN * 128 * 2;   // z, bf16
  int*   counts = (int*)w;                   w += NN * 4;
  int*   starts = (int*)w;                   w += (NN + 8) * 4;
  int*   cursor = (int*)w;                   w += NN * 4;
  float* ev_s   = (float*)w;                 w += NE * 4;
  int*   ec_s   = (int*)w;                   w += NE * 4;

  k_prep<<<256, 256, 0, stream>>>(x, W1, W2, xb, W1t, W2t, counts);
  k_hist<<<NE / 256, 256, 0, stream>>>(erows, counts);
  k_scan<<<1, 1024, 0, stream>>>(counts, starts, cursor);
  k_scatter<<<NE / 256, 256, 0, stream>>>(erows, evals, ecols, cursor, ev_s, ec_s);

  k_gemm<512, 256><<<dim3(64, 4), 256, 0, stream>>>(xb, W1t, g1);
  k_spmm<256><<<NN / 4, 256, 0, stream>>>(starts, ev_s, ec_s, g1, nullptr, h1);
  k_gemm<256, 128><<<dim3(64, 2), 256, 0, stream>>>(h1, W2t, g2);
  k_spmm<128><<<NN / 4, 256, 0, stream>>>(starts, ev_s, ec_s, g2, out_z, zb);
  k_rec<<<dim3(128, 64), 256, 0, stream>>>(zb, out_r0, out_r1);
}

// Round 11
// 653.236 us; speedup vs baseline: 1.9130x; 1.0735x over previous
//
#include <hip/hip_runtime.h>

#define NN 8192
#define NE 262144

typedef short bf16x8 __attribute__((ext_vector_type(8)));
typedef float f32x16 __attribute__((ext_vector_type(16)));
typedef float f32x4 __attribute__((ext_vector_type(4)));

__device__ __forceinline__ unsigned short f2bf(float f) {
  unsigned u = __float_as_uint(f);
  u += 0x7fffu + ((u >> 16) & 1u);
  return (unsigned short)(u >> 16);
}
__device__ __forceinline__ float bflo(unsigned u) { return __uint_as_float(u << 16); }
__device__ __forceinline__ float bfhi(unsigned u) { return __uint_as_float(u & 0xffff0000u); }

// ---- prep: x->bf16, transpose+convert weights, zero counts ----
__global__ void k_prep(const float* __restrict__ x, const float* __restrict__ W1,
                       const float* __restrict__ W2, unsigned short* __restrict__ xb,
                       unsigned short* __restrict__ W1t, unsigned short* __restrict__ W2t,
                       int* __restrict__ counts) {
  int id = blockIdx.x * blockDim.x + threadIdx.x;
  int stride = gridDim.x * blockDim.x;
  for (int t = id; t < (NN * 512) / 4; t += stride) {
    float4 v = *(const float4*)(x + (size_t)t * 4);
    unsigned lo = (unsigned)f2bf(v.x) | ((unsigned)f2bf(v.y) << 16);
    unsigned hi = (unsigned)f2bf(v.z) | ((unsigned)f2bf(v.w) << 16);
    *(uint2*)(xb + (size_t)t * 4) = make_uint2(lo, hi);
  }
  for (int t = id; t < 512 * 256; t += stride) {
    int k = t >> 8, c = t & 255;               // W1[k][c] -> W1t[c][k]
    W1t[c * 512 + k] = f2bf(W1[t]);
  }
  for (int t = id; t < 256 * 128; t += stride) {
    int k = t >> 7, c = t & 127;               // W2[k][c] -> W2t[c][k]
    W2t[c * 256 + k] = f2bf(W2[t]);
  }
  for (int t = id; t < NN; t += stride) counts[t] = 0;
}

// ---- CSR build ----
__global__ void k_hist(const int* __restrict__ rows, int* __restrict__ counts) {
  int id = blockIdx.x * blockDim.x + threadIdx.x;
  if (id < NE) atomicAdd(&counts[rows[id]], 1);
}

__global__ void k_scan(const int* __restrict__ counts, int* __restrict__ starts,
                       int* __restrict__ cursor) {
  __shared__ int sums[1024];
  int t = threadIdx.x;
  int base = t * 8;
  int local[8];
  int s = 0;
  #pragma unroll
  for (int i = 0; i < 8; ++i) { local[i] = s; s += counts[base + i]; }
  sums[t] = s;
  __syncthreads();
  for (int off = 1; off < 1024; off <<= 1) {
    int v = 0;
    if (t >= off) v = sums[t - off];
    __syncthreads();
    sums[t] += v;
    __syncthreads();
  }
  int pre = sums[t] - s;
  #pragma unroll
  for (int i = 0; i < 8; ++i) {
    starts[base + i] = pre + local[i];
    cursor[base + i] = pre + local[i];
  }
  if (t == 1023) starts[NN] = sums[1023];
}

__global__ void k_scatter(const int* __restrict__ rows, const float* __restrict__ vals,
                          const int* __restrict__ cols, int* __restrict__ cursor,
                          float* __restrict__ ev_s, int* __restrict__ ec_s) {
  int id = blockIdx.x * blockDim.x + threadIdx.x;
  if (id < NE) {
    int pos = atomicAdd(&cursor[rows[id]], 1);
    ev_s[pos] = vals[id];
    ec_s[pos] = cols[id];
  }
}

// ---- GEMM: C[8192][N](bf16) = A[8192][K](bf16) * Bt[N][K]^T (bf16 MFMA) ----
// Tile 128x64, BK=64, 512 threads = 8 waves (4 row x 2 col), wave tile 32x32.
template <int K, int N>
__global__ __launch_bounds__(512) void k_gemm(const unsigned short* __restrict__ Ab,
                                              const unsigned short* __restrict__ Bt,
                                              unsigned short* __restrict__ Cb) {
  __shared__ unsigned char As[128 * 64 * 2];   // [128][64] bf16, row=128B, swz ((r&7)<<4)
  __shared__ unsigned char Bs[64 * 64 * 2];
  const int tid = threadIdx.x;
  const int r0 = blockIdx.x * 128, c0 = blockIdx.y * 64;
  const int wid = tid >> 6, lane = tid & 63;
  const int wr = wid >> 1, wc = wid & 1;
  const int lr = lane & 31, lg = lane >> 5;

  f32x16 acc = {};

  for (int kc = 0; kc < K; kc += 64) {
    __syncthreads();
    #pragma unroll
    for (int q = tid; q < 1024; q += 512) {
      int r = q >> 3, s = q & 7;
      float4 v = *(const float4*)(Ab + (size_t)(r0 + r) * K + kc + s * 8);
      *(float4*)(As + r * 128 + ((s * 16) ^ ((r & 7) << 4))) = v;
    }
    {
      int q = tid;
      if (q < 512) {
        int r = q >> 3, s = q & 7;
        float4 v = *(const float4*)(Bt + (size_t)(c0 + r) * K + kc + s * 8);
        *(float4*)(Bs + r * 128 + ((s * 16) ^ ((r & 7) << 4))) = v;
      }
    }
    __syncthreads();
    #pragma unroll
    for (int ks = 0; ks < 4; ++ks) {
      int brow = wc * 32 + lr;
      bf16x8 bf = *(const bf16x8*)(Bs + brow * 128 + ((ks * 32 + lg * 16) ^ ((brow & 7) << 4)));
      int arow = wr * 32 + lr;
      bf16x8 af = *(const bf16x8*)(As + arow * 128 + ((ks * 32 + lg * 16) ^ ((arow & 7) << 4)));
      acc = __builtin_amdgcn_mfma_f32_32x32x16_bf16(bf, af, acc, 0, 0, 0);
    }
  }
  // lane owns row; regs span cols: col(r) = (r&3)+8*(r>>2)+4*lg
  {
    int row = r0 + wr * 32 + lr;
    #pragma unroll
    for (int g = 0; g < 4; ++g) {
      unsigned lo = (unsigned)f2bf(acc[4 * g + 0]) | ((unsigned)f2bf(acc[4 * g + 1]) << 16);
      unsigned hi = (unsigned)f2bf(acc[4 * g + 2]) | ((unsigned)f2bf(acc[4 * g + 3]) << 16);
      int colc = c0 + wc * 32 + 8 * g + 4 * lg;
      *(uint2*)(Cb + (size_t)row * N + colc) = make_uint2(lo, hi);
    }
  }
}

// ---- SPMM: one wave per row, CSR, bf16 gather ----
template <int F>
__global__ __launch_bounds__(256) void k_spmm(const int* __restrict__ starts,
                                              const float* __restrict__ ev_s,
                                              const int* __restrict__ ec_s,
                                              const unsigned short* __restrict__ Sb,
                                              float* __restrict__ outF,
                                              unsigned short* __restrict__ outB) {
  constexpr int V = F / 64;
  int gw = (blockIdx.x * blockDim.x + threadIdx.x) >> 6;
  int lane = threadIdx.x & 63;
  if (gw >= NN) return;
  int s = starts[gw], e = starts[gw + 1];
  float acc[V];
  #pragma unroll
  for (int v = 0; v < V; ++v) acc[v] = 0.f;
  for (int j = s; j < e; ++j) {
    float w = ev_s[j];
    int c = ec_s[j];
    if constexpr (V == 4) {
      uint2 t = *(const uint2*)(Sb + (size_t)c * F + lane * 4);
      acc[0] += w * bflo(t.x); acc[1] += w * bfhi(t.x);
      acc[2] += w * bflo(t.y); acc[3] += w * bfhi(t.y);
    } else {
      unsigned t = *(const unsigned*)(Sb + (size_t)c * F + lane * 2);
      acc[0] += w * bflo(t); acc[1] += w * bfhi(t);
    }
  }
  #pragma unroll
  for (int v = 0; v < V; ++v) acc[v] = fmaxf(acc[v], 0.f);
  if constexpr (V == 4) {
    unsigned lo = (unsigned)f2bf(acc[0]) | ((unsigned)f2bf(acc[1]) << 16);
    unsigned hi = (unsigned)f2bf(acc[2]) | ((unsigned)f2bf(acc[3]) << 16);
    *(uint2*)(outB + (size_t)gw * F + lane * 4) = make_uint2(lo, hi);
  } else {
    unsigned lo = (unsigned)f2bf(acc[0]) | ((unsigned)f2bf(acc[1]) << 16);
    *(unsigned int*)(outB + (size_t)gw * F + lane * 2) = lo;
    if (outF) {
      *(float2*)(outF + (size_t)gw * F + lane * 2) = make_float2(acc[0], acc[1]);
    }
  }
}

// ---- rec = z z^T to two views. Tile 64(i) x 128(j). LDS-transpose epilogue.
// Grid: x = j-tile, y = i-tile -> consecutive blocks write adjacent 512B of the
// SAME rows (fill-like streaming). Plain f32x4 stores (match fill's 6.2TB/s).
__global__ __launch_bounds__(256) void k_rec(const unsigned short* __restrict__ zb,
                                             float* __restrict__ out0,
                                             float* __restrict__ out1) {
  __shared__ unsigned char lds[49152];
  unsigned char* Ai = lds;                 // [64][128] bf16, row=256B, swz ((r&15)<<4)
  unsigned char* Bj = lds + 16384;         // [128][128] bf16
  const int tid = threadIdx.x;
  const int i0 = blockIdx.y * 64, j0 = blockIdx.x * 128;

  for (int q = tid; q < 1024; q += 256) {  // A: 64 rows x 16 slots of 16B
    int r = q >> 4, s = q & 15;
    float4 v = *(const float4*)(zb + (size_t)(i0 + r) * 128 + s * 8);
    *(float4*)(Ai + r * 256 + ((s * 16) ^ ((r & 15) << 4))) = v;
  }
  for (int q = tid; q < 2048; q += 256) {  // B: 128 rows x 16 slots
    int r = q >> 4, s = q & 15;
    float4 v = *(const float4*)(zb + (size_t)(j0 + r) * 128 + s * 8);
    *(float4*)(Bj + r * 256 + ((s * 16) ^ ((r & 15) << 4))) = v;
  }
  __syncthreads();

  const int wid = tid >> 6, lane = tid & 63;
  const int wrow = wid >> 1, wcol = wid & 1;   // wave tile: 32(i) x 64(j)
  const int lr = lane & 31, lg = lane >> 5;

  f32x16 acc[2] = {};
  #pragma unroll
  for (int ks = 0; ks < 8; ++ks) {
    int arow = wrow * 32 + lr;
    bf16x8 af = *(const bf16x8*)(Ai + arow * 256 + ((ks * 32 + lg * 16) ^ ((arow & 15) << 4)));
    #pragma unroll
    for (int m = 0; m < 2; ++m) {
      int brow = wcol * 64 + m * 32 + lr;
      bf16x8 bf = *(const bf16x8*)(Bj + brow * 256 + ((ks * 32 + lg * 16) ^ ((brow & 15) << 4)));
      acc[m] = __builtin_amdgcn_mfma_f32_32x32x16_bf16(bf, af, acc[m], 0, 0, 0);
    }
  }

  // transpose via LDS: T[64][132] f32 (pad -> 16B-aligned rows)
  __syncthreads();                          // all frag reads done; reuse LDS
  float* T = (float*)lds;
  {
    int row = wrow * 32 + lr;               // i within tile
    #pragma unroll
    for (int m = 0; m < 2; ++m) {
      #pragma unroll
      for (int q = 0; q < 4; ++q) {         // acc[m][4q..4q+3] are 4 consecutive cols
        int col = wcol * 64 + m * 32 + 8 * q + 4 * lg;
        f32x4 v = {acc[m][4 * q + 0], acc[m][4 * q + 1], acc[m][4 * q + 2], acc[m][4 * q + 3]};
        *(f32x4*)(T + row * 132 + col) = v;
      }
    }
  }
  __syncthreads();
  // write out: 8 passes, 8 rows/pass, 32 threads/row -> 512B contiguous per row
  {
    int rr = tid >> 5, cc = (tid & 31) * 4;
    #pragma unroll
    for (int p = 0; p < 8; ++p) {
      int row = p * 8 + rr;
      f32x4 v = *(const f32x4*)(T + row * 132 + cc);
      size_t idx = (size_t)(i0 + row) * NN + (size_t)(j0 + cc);
      *(f32x4*)(out0 + idx) = v;
      *(f32x4*)(out1 + idx) = v;
    }
  }
}

extern "C" void kernel_launch(void* const* d_in, const int* in_sizes, int n_in,
                              void* d_out, int out_size, void* d_ws, size_t ws_size,
                              hipStream_t stream) {
  const float* x     = (const float*)d_in[0];
  const float* W1    = (const float*)d_in[1];
  const float* W2    = (const float*)d_in[2];
  const float* evals = (const float*)d_in[3];
  const int*   erows = (const int*)d_in[4];
  const int*   ecols = (const int*)d_in[5];

  float* out_z   = (float*)d_out;                       // [8192][128]
  float* out_r0  = out_z + (size_t)NN * 128;            // view 0
  float* out_r1  = out_r0 + (size_t)NN * NN;            // view 1

  char* w = (char*)d_ws;
  unsigned short* W1t = (unsigned short*)w;  w += 256 * 512 * 2;
  unsigned short* W2t = (unsigned short*)w;  w += 128 * 256 * 2;
  unsigned short* xb  = (unsigned short*)w;  w += (size_t)NN * 512 * 2;
  unsigned short* g1  = (unsigned short*)w;  w += (size_t)NN * 256 * 2;   // x@W1, bf16
  unsigned short* h1  = (unsigned short*)w;  w += (size_t)NN * 256 * 2;   // relu(spmm), bf16
  unsigned short* g2  = (unsigned short*)w;  w += (size_t)NN * 128 * 2;   // h@W2, bf16
  unsigned short* zb  = (unsigned short*)w;  w += (size_t)NN * 128 * 2;   // z, bf16
  int*   counts = (int*)w;                   w += NN * 4;
  int*   starts = (int*)w;                   w += (NN + 8) * 4;
  int*   cursor = (int*)w;                   w += NN * 4;
  float* ev_s   = (float*)w;                 w += NE * 4;
  int*   ec_s   = (int*)w;                   w += NE * 4;

  k_prep<<<256, 256, 0, stream>>>(x, W1, W2, xb, W1t, W2t, counts);
  k_hist<<<NE / 256, 256, 0, stream>>>(erows, counts);
  k_scan<<<1, 1024, 0, stream>>>(counts, starts, cursor);
  k_scatter<<<NE / 256, 256, 0, stream>>>(erows, evals, ecols, cursor, ev_s, ec_s);

  k_gemm<512, 256><<<dim3(64, 4), 512, 0, stream>>>(xb, W1t, g1);
  k_spmm<256><<<NN / 4, 256, 0, stream>>>(starts, ev_s, ec_s, g1, nullptr, h1);
  k_gemm<256, 128><<<dim3(64, 2), 512, 0, stream>>>(h1, W2t, g2);
  k_spmm<128><<<NN / 4, 256, 0, stream>>>(starts, ev_s, ec_s, g2, out_z, zb);
  k_rec<<<dim3(64, 128), 256, 0, stream>>>(zb, out_r0, out_r1);
}